// Round 1
// baseline (572.653 us; speedup 1.0000x reference)
//
#include <hip/hip_runtime.h>

// Problem constants (GRID=192, ISO=0)
#define GN 192           // grid points per axis
#define CN 193           // cells per axis (GN+1)
#define CN2 (CN * CN)    // 37249

// Output layout (float32 elements), in reference return order:
//   verts : CN^3 * 3
//   vmask : CN^3
//   quads : 3 * CN*GN*GN * 4
//   qmask : 3 * CN*GN*GN
#define NV        ((size_t)CN * CN * CN)                  // 7,189,057
#define OFF_VMASK ((size_t)(NV * 3))                      // 21,567,171
#define OFF_QUADS ((size_t)(OFF_VMASK + NV))              // 28,756,228
#define QSEG      ((size_t)CN * GN * GN)                  // 7,114,752 rows per segment
#define OFF_QMASK ((size_t)(OFF_QUADS + 3 * QSEG * 4))    // 114,133,252

typedef float f4 __attribute__((ext_vector_type(4)));

// Non-temporal stores: outputs are write-once streams, never re-read.
// Keep them out of L2 so the 28 MB grid (8x reuse) stays resident.
__device__ __forceinline__ void nts(float* p, float v) {
    __builtin_nontemporal_store(v, p);
}
__device__ __forceinline__ void nts4(f4* p, f4 v) {
    __builtin_nontemporal_store(v, p);
}

// Slow-path load with padding: OOB -> iso+1 = 1.0f
__device__ __forceinline__ float gpad(const float* __restrict__ g, int x, int y, int z) {
    if ((unsigned)x < (unsigned)GN && (unsigned)y < (unsigned)GN && (unsigned)z < (unsigned)GN)
        return g[((size_t)x * GN + y) * GN + z];
    return 1.0f;
}

// ------------------------- fused DMC kernel -------------------------------
// One thread per cell lin = (i*193 + j)*193 + k.
// Changes vs previous version:
//  - interior fast path: one bounds test instead of 8 per-load clamps (97% of threads)
//  - fully branchless 12-edge accumulation (random data => ~every wave hits every
//    branch body anyway; cndmask is strictly cheaper than exec-masked blocks)
//  - verts staged through LDS -> perfectly coalesced contiguous dword stores
//    (stride-3 AoS stores previously tripled L2 write requests on 86 MB)
//  - all output stores non-temporal
//  - no early return (required for __syncthreads); per-write `valid` guards
__global__ __launch_bounds__(256) void dmc_fused(const float* __restrict__ g,
                                                 float* __restrict__ out) {
    __shared__ float vlds[256 * 3];

    const int tid = threadIdx.x;
    const size_t blockBase = (size_t)blockIdx.x * 256;
    const size_t lin = blockBase + tid;
    const bool valid = lin < NV;

    const int linI = (int)lin;
    const int k = linI % CN;
    const int t2 = linI / CN;
    const int j = t2 % CN;
    const int i = t2 / CN;

    // 8 corner values of padded cell: P[i+di][j+dj][k+dk] = grid[i-1+di][j-1+dj][k-1+dk]
    float v000 = 1.f, v100 = 1.f, v010 = 1.f, v110 = 1.f;
    float v001 = 1.f, v101 = 1.f, v011 = 1.f, v111 = 1.f;
    if (valid) {
        // interior iff all of i-1..i, j-1..j, k-1..k within [0, GN)
        const bool interior = ((unsigned)(i - 1) < (unsigned)(GN - 1)) &
                              ((unsigned)(j - 1) < (unsigned)(GN - 1)) &
                              ((unsigned)(k - 1) < (unsigned)(GN - 1));
        if (interior) {
            const float* b = g + ((size_t)(i - 1) * GN + (j - 1)) * GN + (k - 1);
            v000 = b[0];
            v001 = b[1];
            v010 = b[GN];
            v011 = b[GN + 1];
            v100 = b[GN * GN];
            v101 = b[GN * GN + 1];
            v110 = b[GN * GN + GN];
            v111 = b[GN * GN + GN + 1];
        } else {
            v000 = gpad(g, i - 1, j - 1, k - 1);
            v100 = gpad(g, i,     j - 1, k - 1);
            v010 = gpad(g, i - 1, j,     k - 1);
            v110 = gpad(g, i,     j,     k - 1);
            v001 = gpad(g, i - 1, j - 1, k);
            v101 = gpad(g, i,     j - 1, k);
            v011 = gpad(g, i - 1, j,     k);
            v111 = gpad(g, i,     j,     k);
        }
    }

    const bool s000 = v000 < 0.f, s100 = v100 < 0.f, s010 = v010 < 0.f, s110 = v110 < 0.f;
    const bool s001 = v001 < 0.f, s101 = v101 < 0.f, s011 = v011 < 0.f, s111 = v111 < 0.f;

    // ---- dual vertex: mean of iso-crossings on the 12 edges (branchless) ----
    float sx = 0.f, sy = 0.f, sz = 0.f, cf = 0.f;
    auto acc = [&](float vA, float vB, bool sA, bool sB, int axis, float o1, float o2) {
        const bool c = sA != sB;
        const float m = c ? 1.0f : 0.0f;
        // when crossing: vA and vB have strict opposite signs => vB - vA != 0
        const float t = c ? (-vA * __builtin_amdgcn_rcpf(vB - vA)) : 0.0f;
        if (axis == 0)      { sx += t;      sy += m * o1; sz += m * o2; }
        else if (axis == 1) { sx += m * o1; sy += t;      sz += m * o2; }
        else                { sx += m * o1; sy += m * o2; sz += t;      }
        cf += m;
    };
    acc(v000, v100, s000, s100, 0, 0.f, 0.f);
    acc(v010, v110, s010, s110, 0, 1.f, 0.f);
    acc(v001, v101, s001, s101, 0, 0.f, 1.f);
    acc(v011, v111, s011, s111, 0, 1.f, 1.f);
    acc(v000, v010, s000, s010, 1, 0.f, 0.f);
    acc(v100, v110, s100, s110, 1, 1.f, 0.f);
    acc(v001, v011, s001, s011, 1, 0.f, 1.f);
    acc(v101, v111, s101, s111, 1, 1.f, 1.f);
    acc(v000, v001, s000, s001, 2, 0.f, 0.f);
    acc(v100, v101, s100, s101, 2, 1.f, 0.f);
    acc(v010, v011, s010, s011, 2, 0.f, 1.f);
    acc(v110, v111, s110, s111, 2, 1.f, 1.f);

    const float rc = __builtin_amdgcn_rcpf(fmaxf(cf, 1.0f));
    const float inv191 = 1.0f / 191.0f;

    // stride-3 LDS write: gcd(3,32)=1 -> exactly 2 lanes/bank per wave (free)
    vlds[tid * 3 + 0] = ((float)i + sx * rc - 1.0f) * inv191;
    vlds[tid * 3 + 1] = ((float)j + sy * rc - 1.0f) * inv191;
    vlds[tid * 3 + 2] = ((float)k + sz * rc - 1.0f) * inv191;
    __syncthreads();

    // coalesced verts store: 768 contiguous dwords per block
    {
        const size_t gbase = blockBase * 3;
#pragma unroll
        for (int c = 0; c < 3; ++c) {
            const size_t idx = (size_t)tid + 256 * c;
            if (gbase + idx < NV * 3) nts(out + gbase + idx, vlds[idx]);
        }
    }

    if (valid) nts(out + OFF_VMASK + lin, (cf > 0.f) ? 1.0f : 0.0f);

    const float flin = (float)linI;   // cell id of (i,j,k), exact (< 2^24)
    f4* const quads = (f4*)(out + OFF_QUADS);
    float* const qmask = out + OFF_QMASK;

    // ---- segment A: x-directed edge at (a=i, b=j+1, c=k+1); valid j<192 && k<192
    if (valid && j < GN && k < GN) {
        const size_t r = ((size_t)i * GN + j) * GN + k;
        f4 q;
        q.x = flin;                 // cid(i, j,   k)
        q.y = flin + (float)CN;     // cid(i, j+1, k)
        q.z = flin + (float)(CN + 1); // cid(i, j+1, k+1)
        q.w = flin + 1.0f;          // cid(i, j,   k+1)
        nts4(quads + r, q);
        nts(qmask + r, (s011 != s111) ? 1.0f : 0.0f);
    }
    // ---- segment B: y-directed edge at (a=i, b=j, c=k+1); valid i>=1 && k<192
    if (valid && i >= 1 && k < GN) {
        const size_t r = QSEG + ((size_t)(i - 1) * CN + j) * GN + k;
        f4 q;
        q.x = flin - (float)CN2;        // cid(i-1, j, k)
        q.y = flin;                     // cid(i,   j, k)
        q.z = flin + 1.0f;              // cid(i,   j, k+1)
        q.w = flin - (float)(CN2 - 1);  // cid(i-1, j, k+1)
        nts4(quads + r, q);
        nts(qmask + r, (s001 != s011) ? 1.0f : 0.0f);
    }
    // ---- segment C: z-directed edge at (a=i, b=j, c=k); valid i>=1 && j>=1
    if (valid && i >= 1 && j >= 1) {
        const size_t r = 2 * QSEG + ((size_t)(i - 1) * GN + (j - 1)) * CN + k;
        f4 q;
        q.x = flin - (float)(CN2 + CN); // cid(i-1, j-1, k)
        q.y = flin - (float)CN;         // cid(i,   j-1, k)
        q.z = flin;                     // cid(i,   j,   k)
        q.w = flin - (float)CN2;        // cid(i-1, j,   k)
        nts4(quads + r, q);
        nts(qmask + r, (s000 != s001) ? 1.0f : 0.0f);
    }
}

extern "C" void kernel_launch(void* const* d_in, const int* in_sizes, int n_in,
                              void* d_out, int out_size, void* d_ws, size_t ws_size,
                              hipStream_t stream) {
    const float* g = (const float*)d_in[0];
    float* out = (float*)d_out;
    const int nblocks = (int)((NV + 255) / 256);   // 28083
    dmc_fused<<<dim3(nblocks), dim3(256), 0, stream>>>(g, out);
}